// Round 1
// 409.839 us; speedup vs baseline: 1.2710x; 1.2710x over previous
//
#include <hip/hip_runtime.h>

typedef short bf16x8 __attribute__((ext_vector_type(8)));
typedef float f32x4 __attribute__((ext_vector_type(4)));
typedef unsigned u32;
typedef unsigned short u16;
typedef unsigned u32x4v __attribute__((ext_vector_type(4)));
typedef unsigned u32x2v __attribute__((ext_vector_type(2)));

union UV { u32x4v u; bf16x8 v; };

__device__ __forceinline__ u16 f2bf(float f){          // RNE fp32->bf16
  u32 u = __float_as_uint(f);
  u += 0x7FFFu + ((u>>16)&1u);
  return (u16)(u>>16);
}
__device__ __forceinline__ u32 pack2(float lo, float hi){
  return (u32)f2bf(lo) | ((u32)f2bf(hi)<<16);
}
__device__ __forceinline__ bf16x8 cvt8(float4 lo, float4 hi){
  UV t; t.u = (u32x4v){ pack2(lo.x,lo.y), pack2(lo.z,lo.w), pack2(hi.x,hi.y), pack2(hi.z,hi.w) };
  return t.v;
}

// ---------------- K0a: q_scaled[n][d] = SCALE*(emb[n,:]·q_w[d,:] + q_b[d]) -> bf16 ----------------
__global__ void k_qs(const float* __restrict__ emb, const float* __restrict__ q_w,
                     const float* __restrict__ q_b, u16* __restrict__ q_s){
  const int n = blockIdx.x;      // 64
  const int d = threadIdx.x;     // 256
  const float4* er = (const float4*)(emb + n*256);
  const float4* wr = (const float4*)(q_w + d*256);
  float acc = 0.f;
  for(int c=0;c<64;++c){
    float4 e = er[c], w = wr[c];
    acc += e.x*w.x + e.y*w.y + e.z*w.z + e.w*w.w;
  }
  acc += q_b[d];
  q_s[n*256 + d] = f2bf(acc * 0.17677669529663687f);   // 32^-0.5
}

// ---------------- K0b: bias[h][n][m] = rpb[rel_idx(n,m)][h] (fp32) ----------------
__global__ void k_bias(const float* __restrict__ rpb, float* __restrict__ bias){
  const int o = blockIdx.x*256 + threadIdx.x;          // 128 blocks -> 32768
  const int h = o>>12, n = (o>>6)&63, m = o&63;
  const int idx = ((n>>3)-(m>>3)+7)*15 + ((n&7)-(m&7)+7);
  bias[o] = rpb[idx*8 + h];
}

// ---------------- K0c: convert kv_w (131072 f32) and proj_w (65536 f32) to bf16 ----------------
__global__ void k_wcvt(const float* __restrict__ kv_w, const float* __restrict__ proj_w,
                       u32* __restrict__ kvb, u32* __restrict__ pjb){
  const int i = blockIdx.x*256 + threadIdx.x;          // 384 blocks -> 98304
  if(i < 65536) kvb[i] = pack2(kv_w[2*i], kv_w[2*i+1]);
  else { int j = i - 65536; pjb[j] = pack2(proj_w[2*j], proj_w[2*j+1]); }
}

// ---------------- Fused per-window kernel: KV GEMM -> attention -> proj ----------------
// LDS regions:
//   A (36864 B): k[64 rows][256 cols] bf16, byte ^= ((row&7)<<4)   ... then P (4 waves x 64 x 36 u32)
//   B (32768 B): vT head-blocked [h][32 e][64 m] bf16, byte ^= ((e&7)<<4)
//                ... then ao head-blocked [h][64 row][32 cc] bf16, byte ^= ((row&7)<<4)
__global__ __launch_bounds__(256,2) void k_fused(const float* __restrict__ x, const u16* __restrict__ kvw,
                                                 const float* __restrict__ kv_b, const u16* __restrict__ q_s,
                                                 const float* __restrict__ bias, const u16* __restrict__ pjw,
                                                 const float* __restrict__ proj_b, float* __restrict__ out){
  __shared__ char smem[69632];
  char* regA = smem;
  char* regB = smem + 36864;

  const int bw = blockIdx.x;
  const int b = bw>>8, h1 = (bw>>4)&15, w1 = bw&15;
  const int base = b*4194304 + h1*262144 + w1*2048;
  const int tid = threadIdx.x;
  const int w = tid>>6, l = tid&63, g = l>>4, li = l&15;

  // ---------- Phase 1: KV GEMM (A from global x with fp32->bf16 cvt, B from global kvw) ----------
  {
    f32x4 acc[4][8];
    #pragma unroll
    for(int ct=0;ct<8;++ct){
      float bv = kv_b[w*128 + ct*16 + li];
      #pragma unroll
      for(int rt=0;rt<4;++rt) acc[rt][ct] = (f32x4){bv,bv,bv,bv};
    }
    for(int ks=0;ks<8;++ks){
      bf16x8 a[4];
      #pragma unroll
      for(int rt=0;rt<4;++rt){
        int n = rt*16 + li;
        const float* ap = x + base + (n>>3)*32768 + (n&7)*256 + ks*32 + g*8;
        a[rt] = cvt8(*(const float4*)ap, *(const float4*)(ap+4));
      }
      #pragma unroll
      for(int ct=0;ct<8;++ct){
        bf16x8 bfr = *(const bf16x8*)(kvw + (w*128 + ct*16 + li)*256 + ks*32 + g*8);
        #pragma unroll
        for(int rt=0;rt<4;++rt)
          acc[rt][ct] = __builtin_amdgcn_mfma_f32_16x16x32_bf16(a[rt], bfr, acc[rt][ct], 0,0,0);
      }
    }
    if(w < 2){            // k half -> region A, swizzled row-major
      #pragma unroll
      for(int ct=0;ct<8;++ct){
        int col = w*128 + ct*16 + li;
        #pragma unroll
        for(int rt=0;rt<4;++rt)
          #pragma unroll
          for(int r=0;r<4;++r){
            int row = rt*16 + 4*g + r;
            *(u16*)(regA + ((row*512 + col*2) ^ ((row&7)<<4))) = f2bf(acc[rt][ct][r]);
          }
      }
    } else {              // v half -> region B transposed, head-blocked, swizzled
      #pragma unroll
      for(int ct=0;ct<8;++ct){
        int c2 = (w-2)*128 + ct*16 + li;    // 0..255
        int hv = c2>>5, e = c2&31;
        #pragma unroll
        for(int rt=0;rt<4;++rt){
          u32x2v d;
          d[0] = pack2(acc[rt][ct][0], acc[rt][ct][1]);
          d[1] = pack2(acc[rt][ct][2], acc[rt][ct][3]);
          int m0 = rt*16 + 4*g;
          *(u32x2v*)(regB + (((hv*32 + e)*128 + m0*2) ^ ((e&7)<<4))) = d;
        }
      }
    }
  }
  __syncthreads();

  // ---------- Phase 2: preload q and k fragments for BOTH heads (frees region A for P) ----------
  bf16x8 qf[2][4], kf[2][4];
  #pragma unroll
  for(int hh=0;hh<2;++hh){
    const int h = w + 4*hh;
    #pragma unroll
    for(int rt=0;rt<4;++rt) qf[hh][rt] = *(const bf16x8*)(q_s + (rt*16+li)*256 + h*32 + g*8);
    #pragma unroll
    for(int ct=0;ct<4;++ct){
      int row = ct*16 + li;
      kf[hh][ct] = *(const bf16x8*)(regA + ((row*512 + (h*32+g*8)*2) ^ ((row&7)<<4)));
    }
  }
  __syncthreads();   // all k reads done -> region A becomes the per-wave P buffer

  u32* pb = (u32*)regA + w*2304;    // 64 rows x 36 u32 per wave
  const int odd = l & 1;

  // ---------- Phase 3: attention, wave w does heads w and w+4 ----------
  #pragma unroll
  for(int hh=0;hh<2;++hh){
    const int h = w + 4*hh;
    // S = q_scaled · k^T, accumulator initialized with bias
    f32x4 S[4][4];
    #pragma unroll
    for(int rt=0;rt<4;++rt){
      #pragma unroll
      for(int ct=0;ct<4;++ct){
        const float* bp = bias + h*4096 + (rt*16 + 4*g)*64 + ct*16 + li;
        f32x4 c = { bp[0], bp[64], bp[128], bp[192] };
        S[rt][ct] = __builtin_amdgcn_mfma_f32_16x16x32_bf16(qf[hh][rt], kf[hh][ct], c, 0,0,0);
      }
    }
    // in-register softmax: row n = rt*16+4g+r lives in the 16-lane (li) group
    float rs[4][4];
    #pragma unroll
    for(int rt=0;rt<4;++rt){
      #pragma unroll
      for(int r=0;r<4;++r){
        float m_ = fmaxf(fmaxf(S[rt][0][r],S[rt][1][r]), fmaxf(S[rt][2][r],S[rt][3][r]));
        m_ = fmaxf(m_, __shfl_xor(m_,1));
        m_ = fmaxf(m_, __shfl_xor(m_,2));
        m_ = fmaxf(m_, __shfl_xor(m_,4));
        m_ = fmaxf(m_, __shfl_xor(m_,8));
        float e0 = __expf(S[rt][0][r]-m_), e1 = __expf(S[rt][1][r]-m_);
        float e2 = __expf(S[rt][2][r]-m_), e3 = __expf(S[rt][3][r]-m_);
        S[rt][0][r]=e0; S[rt][1][r]=e1; S[rt][2][r]=e2; S[rt][3][r]=e3;
        float s_ = e0+e1+e2+e3;
        s_ += __shfl_xor(s_,1); s_ += __shfl_xor(s_,2); s_ += __shfl_xor(s_,4); s_ += __shfl_xor(s_,8);
        rs[rt][r] = 1.0f/s_;
      }
    }
    // C-layout -> A-layout transpose of P via LDS; lane-paired u32 writes
    #pragma unroll
    for(int rt=0;rt<4;++rt){
      #pragma unroll
      for(int ct=0;ct<4;++ct){
        float v0=S[rt][ct][0], v1=S[rt][ct][1], v2=S[rt][ct][2], v3=S[rt][ct][3];
        float o0=__shfl_xor(v0,1), o1=__shfl_xor(v1,1), o2=__shfl_xor(v2,1), o3=__shfl_xor(v3,1);
        u32 d0 = odd ? pack2(o2,v2) : pack2(v0,o0);
        u32 d1 = odd ? pack2(o3,v3) : pack2(v1,o1);
        int r0 = odd ? 2 : 0;
        int cp = ct*8 + (li>>1);
        pb[(rt*16 + 4*g + r0    )*36 + cp] = d0;
        pb[(rt*16 + 4*g + r0 + 1)*36 + cp] = d1;
      }
    }
    // O = P · v  (vT from LDS region B, swizzled)
    f32x4 O[4][2];
    #pragma unroll
    for(int rt=0;rt<4;++rt){ O[rt][0]=(f32x4){0,0,0,0}; O[rt][1]=(f32x4){0,0,0,0}; }
    #pragma unroll
    for(int ks=0;ks<2;++ks){
      bf16x8 pf[4];
      #pragma unroll
      for(int rt=0;rt<4;++rt){
        UV t; t.u = *(const u32x4v*)(pb + (rt*16+li)*36 + ks*16 + g*4);
        pf[rt] = t.v;
      }
      #pragma unroll
      for(int c2=0;c2<2;++c2){
        int e = c2*16 + li;
        bf16x8 vf = *(const bf16x8*)(regB + (((h*32 + e)*128 + (ks*32+g*8)*2) ^ ((e&7)<<4)));
        #pragma unroll
        for(int rt=0;rt<4;++rt)
          O[rt][c2] = __builtin_amdgcn_mfma_f32_16x16x32_bf16(pf[rt], vf, O[rt][c2], 0,0,0);
      }
    }
    // epilogue: divide by softmax denom, store ao into region B chunk h (vT[h] is dead, own wave only)
    #pragma unroll
    for(int rt=0;rt<4;++rt)
      #pragma unroll
      for(int c2=0;c2<2;++c2)
        #pragma unroll
        for(int r=0;r<4;++r){
          int row = rt*16 + 4*g + r;
          *(u16*)(regB + h*4096 + ((row*64 + (c2*16+li)*2) ^ ((row&7)<<4))) = f2bf(O[rt][c2][r]*rs[rt][r]);
        }
  }
  __syncthreads();

  // ---------- Phase 4: proj GEMM (A from ao in LDS, B from global pjw) ----------
  {
    f32x4 acc[4][4];
    #pragma unroll
    for(int ct=0;ct<4;++ct){
      float bv = proj_b[w*64 + ct*16 + li];
      #pragma unroll
      for(int rt=0;rt<4;++rt) acc[rt][ct] = (f32x4){bv,bv,bv,bv};
    }
    for(int ks=0;ks<8;++ks){   // K-step ks maps exactly to ao head-chunk ks (32 cols per head)
      bf16x8 a[4];
      #pragma unroll
      for(int rt=0;rt<4;++rt){
        int row = rt*16 + li;
        a[rt] = *(const bf16x8*)(regB + ks*4096 + ((row*64 + g*16) ^ ((row&7)<<4)));
      }
      #pragma unroll
      for(int ct=0;ct<4;++ct){
        bf16x8 bfr = *(const bf16x8*)(pjw + (w*64 + ct*16 + li)*256 + ks*32 + g*8);
        #pragma unroll
        for(int rt=0;rt<4;++rt)
          acc[rt][ct] = __builtin_amdgcn_mfma_f32_16x16x32_bf16(a[rt], bfr, acc[rt][ct], 0,0,0);
      }
    }
    #pragma unroll
    for(int rt=0;rt<4;++rt)
      #pragma unroll
      for(int ct=0;ct<4;++ct)
        #pragma unroll
        for(int r=0;r<4;++r)
          out[(bw*64 + rt*16 + 4*g + r)*256 + w*64 + ct*16 + li] = acc[rt][ct][r];
  }
}

extern "C" void kernel_launch(void* const* d_in, const int* in_sizes, int n_in,
                              void* d_out, int out_size, void* d_ws, size_t ws_size,
                              hipStream_t stream){
  (void)in_sizes; (void)n_in; (void)out_size;
  const float* x      = (const float*)d_in[0];
  const float* emb    = (const float*)d_in[1];
  const float* rpb    = (const float*)d_in[2];
  const float* q_w    = (const float*)d_in[3];
  const float* q_b    = (const float*)d_in[4];
  const float* kv_w   = (const float*)d_in[5];
  const float* kv_b   = (const float*)d_in[6];
  const float* proj_w = (const float*)d_in[7];
  const float* proj_b = (const float*)d_in[8];
  float* out = (float*)d_out;

  // ws layout (bytes): q_s 32K | bias 128K | kvw_bf 256K | pjw_bf 128K
  char* ws = (char*)d_ws;
  if(ws_size < (size_t)557056) return;   // diagnostic: out stays zero if ws too small
  u16* q_s   = (u16*)(ws);
  float* bias= (float*)(ws + 32768);
  u32* kvb   = (u32*)(ws + 163840);
  u32* pjb   = (u32*)(ws + 425984);

  k_qs   <<<  64, 256, 0, stream>>>(emb, q_w, q_b, q_s);
  k_bias <<< 128, 256, 0, stream>>>(rpb, bias);
  k_wcvt <<< 384, 256, 0, stream>>>(kv_w, proj_w, kvb, pjb);
  k_fused<<<2048, 256, 0, stream>>>(x, (const u16*)kvb, kv_b, q_s, bias,
                                    (const u16*)pjb, proj_b, out);
}

// Round 2
// 402.479 us; speedup vs baseline: 1.2943x; 1.0183x over previous
//
#include <hip/hip_runtime.h>

typedef short bf16x8 __attribute__((ext_vector_type(8)));
typedef float f32x4 __attribute__((ext_vector_type(4)));
typedef unsigned u32;
typedef unsigned short u16;
typedef unsigned u32x4v __attribute__((ext_vector_type(4)));
typedef unsigned u32x2v __attribute__((ext_vector_type(2)));

union UV { u32x4v u; bf16x8 v; };

__device__ __forceinline__ u16 f2bf(float f){          // RNE fp32->bf16
  u32 u = __float_as_uint(f);
  u += 0x7FFFu + ((u>>16)&1u);
  return (u16)(u>>16);
}
__device__ __forceinline__ u32 pack2(float lo, float hi){
  return (u32)f2bf(lo) | ((u32)f2bf(hi)<<16);
}

// ---------------- K0a: q_scaled[n][d] = SCALE*(emb[n,:]·q_w[d,:] + q_b[d]) -> bf16 ----------------
__global__ void k_qs(const float* __restrict__ emb, const float* __restrict__ q_w,
                     const float* __restrict__ q_b, u16* __restrict__ q_s){
  const int n = blockIdx.x;      // 64
  const int d = threadIdx.x;     // 256
  const float4* er = (const float4*)(emb + n*256);
  const float4* wr = (const float4*)(q_w + d*256);
  float acc = 0.f;
  for(int c=0;c<64;++c){
    float4 e = er[c], w = wr[c];
    acc += e.x*w.x + e.y*w.y + e.z*w.z + e.w*w.w;
  }
  acc += q_b[d];
  q_s[n*256 + d] = f2bf(acc * 0.17677669529663687f);   // 32^-0.5
}

// ---------------- K0b: bias[h][n][m] = rpb[rel_idx(n,m)][h] (fp32) ----------------
__global__ void k_bias(const float* __restrict__ rpb, float* __restrict__ bias){
  const int o = blockIdx.x*256 + threadIdx.x;          // 128 blocks -> 32768
  const int h = o>>12, n = (o>>6)&63, m = o&63;
  const int idx = ((n>>3)-(m>>3)+7)*15 + ((n&7)-(m&7)+7);
  bias[o] = rpb[idx*8 + h];
}

// ---------------- K0c: convert kv_w (131072 f32) and proj_w (65536 f32) to bf16 ----------------
__global__ void k_wcvt(const float* __restrict__ kv_w, const float* __restrict__ proj_w,
                       u32* __restrict__ kvb, u32* __restrict__ pjb){
  const int i = blockIdx.x*256 + threadIdx.x;          // 384 blocks -> 98304
  if(i < 65536) kvb[i] = pack2(kv_w[2*i], kv_w[2*i+1]);
  else { int j = i - 65536; pjb[j] = pack2(proj_w[2*j], proj_w[2*j+1]); }
}

// ---------------- Fused per-window kernel: x->LDS(bf16) -> KV GEMM -> attention -> proj ----------------
// LDS region A (36864 B): x_bf16[64][256] swz -> k[64][256] swz -> P (4 waves x 64 x 36 u32)
// LDS region B (32768 B): vT head-blocked [h][32 e][64 m] swz -> ao head-blocked [h][64 row][32 cc] swz
// swizzle everywhere: byte ^= ((row&7)<<4), row = linear_byte>>9 (A) or per-tile row
__global__ __launch_bounds__(256,2) void k_fused(const float* __restrict__ x, const u16* __restrict__ kvw,
                                                 const float* __restrict__ kv_b, const u16* __restrict__ q_s,
                                                 const float* __restrict__ bias, const u16* __restrict__ pjw,
                                                 const float* __restrict__ proj_b, float* __restrict__ out){
  __shared__ char smem[69632];
  char* regA = smem;
  char* regB = smem + 36864;

  const int bw = blockIdx.x;
  const int b = bw>>8, h1 = (bw>>4)&15, w1 = bw&15;
  const int base = b*4194304 + h1*262144 + w1*2048;
  const int tid = threadIdx.x;
  const int w = tid>>6, l = tid&63, g = l>>4, li = l&15;

  // ---------- Phase 0: cooperative stage x window -> regA as bf16 (swizzled) ----------
  {
    #pragma unroll
    for(int i=0;i<8;++i){
      int p = i*256 + tid;                 // 16B-pair index 0..2047
      int n = p>>5;                        // token row 0..63
      int c4 = (2*p)&63;                   // f4 index within row (even)
      const float4* gp = (const float4*)(x + base + (n>>3)*32768 + (n&7)*256 + c4*4);
      float4 lo = gp[0], hi = gp[1];
      u32x4v d = { pack2(lo.x,lo.y), pack2(lo.z,lo.w), pack2(hi.x,hi.y), pack2(hi.z,hi.w) };
      *(u32x4v*)(regA + ((p*16) ^ ((n&7)<<4))) = d;
    }
  }
  __syncthreads();

  // ---------- Phase 1: KV GEMM (A-frags from LDS, B from global kvw, L2-hot) ----------
  {
    f32x4 acc[4][8];
    #pragma unroll
    for(int ct=0;ct<8;++ct){
      float bv = kv_b[w*128 + ct*16 + li];
      #pragma unroll
      for(int rt=0;rt<4;++rt) acc[rt][ct] = (f32x4){bv,bv,bv,bv};
    }
    for(int ks=0;ks<8;++ks){
      bf16x8 a[4];
      #pragma unroll
      for(int rt=0;rt<4;++rt){
        int n = rt*16 + li;
        a[rt] = *(const bf16x8*)(regA + ((n*512 + ks*64 + g*16) ^ ((n&7)<<4)));
      }
      #pragma unroll
      for(int ct=0;ct<8;++ct){
        bf16x8 bfr = *(const bf16x8*)(kvw + (w*128 + ct*16 + li)*256 + ks*32 + g*8);
        #pragma unroll
        for(int rt=0;rt<4;++rt)
          acc[rt][ct] = __builtin_amdgcn_mfma_f32_16x16x32_bf16(a[rt], bfr, acc[rt][ct], 0,0,0);
      }
    }
    __syncthreads();   // all x reads done -> regA reusable for k

    if(w < 2){            // k half -> regA, swizzled row-major (overwrites x image)
      #pragma unroll
      for(int ct=0;ct<8;++ct){
        int col = w*128 + ct*16 + li;
        #pragma unroll
        for(int rt=0;rt<4;++rt)
          #pragma unroll
          for(int r=0;r<4;++r){
            int row = rt*16 + 4*g + r;
            *(u16*)(regA + ((row*512 + col*2) ^ ((row&7)<<4))) = f2bf(acc[rt][ct][r]);
          }
      }
    } else {              // v half -> regB transposed, head-blocked, swizzled
      #pragma unroll
      for(int ct=0;ct<8;++ct){
        int c2 = (w-2)*128 + ct*16 + li;    // 0..255
        int hv = c2>>5, e = c2&31;
        #pragma unroll
        for(int rt=0;rt<4;++rt){
          u32x2v d;
          d[0] = pack2(acc[rt][ct][0], acc[rt][ct][1]);
          d[1] = pack2(acc[rt][ct][2], acc[rt][ct][3]);
          int m0 = rt*16 + 4*g;
          *(u32x2v*)(regB + (((hv*32 + e)*128 + m0*2) ^ ((e&7)<<4))) = d;
        }
      }
    }
  }
  __syncthreads();

  // ---------- Phase 2: preload q and k fragments for BOTH heads (frees regA for P) ----------
  bf16x8 qf[2][4], kf[2][4];
  #pragma unroll
  for(int hh=0;hh<2;++hh){
    const int h = w + 4*hh;
    #pragma unroll
    for(int rt=0;rt<4;++rt) qf[hh][rt] = *(const bf16x8*)(q_s + (rt*16+li)*256 + h*32 + g*8);
    #pragma unroll
    for(int ct=0;ct<4;++ct){
      int row = ct*16 + li;
      kf[hh][ct] = *(const bf16x8*)(regA + ((row*512 + (h*32+g*8)*2) ^ ((row&7)<<4)));
    }
  }
  __syncthreads();   // all k reads done -> regA becomes the per-wave P buffer

  u32* pb = (u32*)regA + w*2304;    // 64 rows x 36 u32 per wave
  const int odd = l & 1;

  // ---------- Phase 3: attention, wave w does heads w and w+4 ----------
  #pragma unroll
  for(int hh=0;hh<2;++hh){
    const int h = w + 4*hh;
    // S = q_scaled · k^T, accumulator initialized with bias
    f32x4 S[4][4];
    #pragma unroll
    for(int rt=0;rt<4;++rt){
      #pragma unroll
      for(int ct=0;ct<4;++ct){
        const float* bp = bias + h*4096 + (rt*16 + 4*g)*64 + ct*16 + li;
        f32x4 c = { bp[0], bp[64], bp[128], bp[192] };
        S[rt][ct] = __builtin_amdgcn_mfma_f32_16x16x32_bf16(qf[hh][rt], kf[hh][ct], c, 0,0,0);
      }
    }
    // in-register softmax: row n = rt*16+4g+r lives in the 16-lane (li) group
    float rs[4][4];
    #pragma unroll
    for(int rt=0;rt<4;++rt){
      #pragma unroll
      for(int r=0;r<4;++r){
        float m_ = fmaxf(fmaxf(S[rt][0][r],S[rt][1][r]), fmaxf(S[rt][2][r],S[rt][3][r]));
        m_ = fmaxf(m_, __shfl_xor(m_,1));
        m_ = fmaxf(m_, __shfl_xor(m_,2));
        m_ = fmaxf(m_, __shfl_xor(m_,4));
        m_ = fmaxf(m_, __shfl_xor(m_,8));
        float e0 = __expf(S[rt][0][r]-m_), e1 = __expf(S[rt][1][r]-m_);
        float e2 = __expf(S[rt][2][r]-m_), e3 = __expf(S[rt][3][r]-m_);
        S[rt][0][r]=e0; S[rt][1][r]=e1; S[rt][2][r]=e2; S[rt][3][r]=e3;
        float s_ = e0+e1+e2+e3;
        s_ += __shfl_xor(s_,1); s_ += __shfl_xor(s_,2); s_ += __shfl_xor(s_,4); s_ += __shfl_xor(s_,8);
        rs[rt][r] = 1.0f/s_;
      }
    }
    // C-layout -> A-layout transpose of P via LDS; lane-paired u32 writes
    #pragma unroll
    for(int rt=0;rt<4;++rt){
      #pragma unroll
      for(int ct=0;ct<4;++ct){
        float v0=S[rt][ct][0], v1=S[rt][ct][1], v2=S[rt][ct][2], v3=S[rt][ct][3];
        float o0=__shfl_xor(v0,1), o1=__shfl_xor(v1,1), o2=__shfl_xor(v2,1), o3=__shfl_xor(v3,1);
        u32 d0 = odd ? pack2(o2,v2) : pack2(v0,o0);
        u32 d1 = odd ? pack2(o3,v3) : pack2(v1,o1);
        int r0 = odd ? 2 : 0;
        int cp = ct*8 + (li>>1);
        pb[(rt*16 + 4*g + r0    )*36 + cp] = d0;
        pb[(rt*16 + 4*g + r0 + 1)*36 + cp] = d1;
      }
    }
    // O = P · v  (vT from LDS region B, swizzled)
    f32x4 O[4][2];
    #pragma unroll
    for(int rt=0;rt<4;++rt){ O[rt][0]=(f32x4){0,0,0,0}; O[rt][1]=(f32x4){0,0,0,0}; }
    #pragma unroll
    for(int ks=0;ks<2;++ks){
      bf16x8 pf[4];
      #pragma unroll
      for(int rt=0;rt<4;++rt){
        UV t; t.u = *(const u32x4v*)(pb + (rt*16+li)*36 + ks*16 + g*4);
        pf[rt] = t.v;
      }
      #pragma unroll
      for(int c2=0;c2<2;++c2){
        int e = c2*16 + li;
        bf16x8 vf = *(const bf16x8*)(regB + (((h*32 + e)*128 + (ks*32+g*8)*2) ^ ((e&7)<<4)));
        #pragma unroll
        for(int rt=0;rt<4;++rt)
          O[rt][c2] = __builtin_amdgcn_mfma_f32_16x16x32_bf16(pf[rt], vf, O[rt][c2], 0,0,0);
      }
    }
    // epilogue: divide by softmax denom, store ao into regB chunk h (vT[h] is dead, own wave only)
    #pragma unroll
    for(int rt=0;rt<4;++rt)
      #pragma unroll
      for(int c2=0;c2<2;++c2)
        #pragma unroll
        for(int r=0;r<4;++r){
          int row = rt*16 + 4*g + r;
          *(u16*)(regB + h*4096 + ((row*64 + (c2*16+li)*2) ^ ((row&7)<<4))) = f2bf(O[rt][c2][r]*rs[rt][r]);
        }
  }
  __syncthreads();

  // ---------- Phase 4: proj GEMM (A from ao in LDS, B from global pjw) ----------
  {
    f32x4 acc[4][4];
    #pragma unroll
    for(int ct=0;ct<4;++ct){
      float bv = proj_b[w*64 + ct*16 + li];
      #pragma unroll
      for(int rt=0;rt<4;++rt) acc[rt][ct] = (f32x4){bv,bv,bv,bv};
    }
    for(int ks=0;ks<8;++ks){   // K-step ks maps exactly to ao head-chunk ks (32 cols per head)
      bf16x8 a[4];
      #pragma unroll
      for(int rt=0;rt<4;++rt){
        int row = rt*16 + li;
        a[rt] = *(const bf16x8*)(regB + ks*4096 + ((row*64 + g*16) ^ ((row&7)<<4)));
      }
      #pragma unroll
      for(int ct=0;ct<4;++ct){
        bf16x8 bfr = *(const bf16x8*)(pjw + (w*64 + ct*16 + li)*256 + ks*32 + g*8);
        #pragma unroll
        for(int rt=0;rt<4;++rt)
          acc[rt][ct] = __builtin_amdgcn_mfma_f32_16x16x32_bf16(a[rt], bfr, acc[rt][ct], 0,0,0);
      }
    }
    #pragma unroll
    for(int rt=0;rt<4;++rt)
      #pragma unroll
      for(int ct=0;ct<4;++ct)
        #pragma unroll
        for(int r=0;r<4;++r)
          out[(bw*64 + rt*16 + 4*g + r)*256 + w*64 + ct*16 + li] = acc[rt][ct][r];
  }
}

extern "C" void kernel_launch(void* const* d_in, const int* in_sizes, int n_in,
                              void* d_out, int out_size, void* d_ws, size_t ws_size,
                              hipStream_t stream){
  (void)in_sizes; (void)n_in; (void)out_size;
  const float* x      = (const float*)d_in[0];
  const float* emb    = (const float*)d_in[1];
  const float* rpb    = (const float*)d_in[2];
  const float* q_w    = (const float*)d_in[3];
  const float* q_b    = (const float*)d_in[4];
  const float* kv_w   = (const float*)d_in[5];
  const float* kv_b   = (const float*)d_in[6];
  const float* proj_w = (const float*)d_in[7];
  const float* proj_b = (const float*)d_in[8];
  float* out = (float*)d_out;

  // ws layout (bytes): q_s 32K | bias 128K | kvw_bf 256K | pjw_bf 128K
  char* ws = (char*)d_ws;
  if(ws_size < (size_t)557056) return;   // diagnostic: out stays zero if ws too small
  u16* q_s   = (u16*)(ws);
  float* bias= (float*)(ws + 32768);
  u32* kvb   = (u32*)(ws + 163840);
  u32* pjb   = (u32*)(ws + 425984);

  k_qs   <<<  64, 256, 0, stream>>>(emb, q_w, q_b, q_s);
  k_bias <<< 128, 256, 0, stream>>>(rpb, bias);
  k_wcvt <<< 384, 256, 0, stream>>>(kv_w, proj_w, kvb, pjb);
  k_fused<<<2048, 256, 0, stream>>>(x, (const u16*)kvb, kv_b, q_s, bias,
                                    (const u16*)pjb, proj_b, out);
}

// Round 3
// 364.698 us; speedup vs baseline: 1.4284x; 1.1036x over previous
//
#include <hip/hip_runtime.h>

typedef short bf16x8 __attribute__((ext_vector_type(8)));
typedef float f32x4 __attribute__((ext_vector_type(4)));
typedef float f32x16 __attribute__((ext_vector_type(16)));
typedef unsigned u32;
typedef unsigned short u16;
typedef unsigned u32x4v __attribute__((ext_vector_type(4)));
typedef unsigned u32x2v __attribute__((ext_vector_type(2)));

union UV { u32x4v u; bf16x8 v; };

__device__ __forceinline__ u16 f2bf(float f){          // RNE fp32->bf16
  u32 u = __float_as_uint(f);
  u += 0x7FFFu + ((u>>16)&1u);
  return (u16)(u>>16);
}
__device__ __forceinline__ u32 pack2(float lo, float hi){
  return (u32)f2bf(lo) | ((u32)f2bf(hi)<<16);
}

// ---------------- K0a: q_scaled[n][d] = SCALE*(emb[n,:]·q_w[d,:] + q_b[d]) -> bf16 ----------------
__global__ void k_qs(const float* __restrict__ emb, const float* __restrict__ q_w,
                     const float* __restrict__ q_b, u16* __restrict__ q_s){
  const int n = blockIdx.x;      // 64
  const int d = threadIdx.x;     // 256
  const float4* er = (const float4*)(emb + n*256);
  const float4* wr = (const float4*)(q_w + d*256);
  float acc = 0.f;
  for(int c=0;c<64;++c){
    float4 e = er[c], w = wr[c];
    acc += e.x*w.x + e.y*w.y + e.z*w.z + e.w*w.w;
  }
  acc += q_b[d];
  q_s[n*256 + d] = f2bf(acc * 0.17677669529663687f);   // 32^-0.5
}

// ---------------- K0b: bias[h][n][m] = rpb[rel_idx(n,m)][h] (fp32) ----------------
__global__ void k_bias(const float* __restrict__ rpb, float* __restrict__ bias){
  const int o = blockIdx.x*256 + threadIdx.x;          // 128 blocks -> 32768
  const int h = o>>12, n = (o>>6)&63, m = o&63;
  const int idx = ((n>>3)-(m>>3)+7)*15 + ((n&7)-(m&7)+7);
  bias[o] = rpb[idx*8 + h];
}

// ---------------- K0c: convert kv_w (131072 f32) and proj_w (65536 f32) to bf16 ----------------
__global__ void k_wcvt(const float* __restrict__ kv_w, const float* __restrict__ proj_w,
                       u32* __restrict__ kvb, u32* __restrict__ pjb){
  const int i = blockIdx.x*256 + threadIdx.x;          // 384 blocks -> 98304
  if(i < 65536) kvb[i] = pack2(kv_w[2*i], kv_w[2*i+1]);
  else { int j = i - 65536; pjb[j] = pack2(proj_w[2*j], proj_w[2*j+1]); }
}

// ---------------- Fused per-window kernel, 8 waves, one head per wave ----------------
// Single 32KB LDS region, reused in sequence:
//   x_bf16[64 tok][256 ch] swz  ->  k[64 tok][256 ch] swz  ->  vT[8 h][32 e][64 m] swz
//   -> ao[8 h][64 n][32 e] swz (per-head chunk overwrites own vT chunk)
// swizzles: row-major tiles use byte ^= ((row&7)<<4)
__global__ __launch_bounds__(512,4) void k_fused(const float* __restrict__ x, const u16* __restrict__ kvw,
                                                 const float* __restrict__ kv_b, const u16* __restrict__ q_s,
                                                 const float* __restrict__ bias, const u16* __restrict__ pjw,
                                                 const float* __restrict__ proj_b, float* __restrict__ out){
  __shared__ char R1[32768];

  const int bw = blockIdx.x;
  const int b = bw>>8, h1 = (bw>>4)&15, w1 = bw&15;
  const int base = b*4194304 + h1*262144 + w1*2048;
  const int tid = threadIdx.x;
  const int w = tid>>6, l = tid&63, g = l>>4, li = l&15;
  const int l31 = l&31, hi = l>>5;

  // ---------- Phase 0: cooperative stage x window -> R1 as bf16 (swizzled) ----------
  #pragma unroll
  for(int i=0;i<4;++i){
    int p = i*512 + tid;                 // 16B-pair index 0..2047
    int n = p>>5;                        // token row 0..63
    int c4 = (2*p)&63;                   // f4 index within row (even)
    const float4* gp = (const float4*)(x + base + (n>>3)*32768 + (n&7)*256 + c4*4);
    float4 lo = gp[0], hh = gp[1];
    u32x4v d = { pack2(lo.x,lo.y), pack2(lo.z,lo.w), pack2(hh.x,hh.y), pack2(hh.z,hh.w) };
    *(u32x4v*)(R1 + ((p*16) ^ ((n&7)<<4)));
    *(u32x4v*)(R1 + ((p*16) ^ ((n&7)<<4))) = d;
  }
  __syncthreads();

  // ---------- Phase 1: KV GEMM. wave w computes output cols w*64..w*64+63 ----------
  f32x4 acc[4][4];
  #pragma unroll
  for(int ct=0;ct<4;++ct){
    float bv = kv_b[w*64 + ct*16 + li];
    #pragma unroll
    for(int rt=0;rt<4;++rt) acc[rt][ct] = (f32x4){bv,bv,bv,bv};
  }
  for(int ks=0;ks<8;++ks){
    bf16x8 a[4];
    #pragma unroll
    for(int rt=0;rt<4;++rt){
      int n = rt*16 + li;
      a[rt] = *(const bf16x8*)(R1 + ((n*512 + ks*64 + g*16) ^ ((n&7)<<4)));
    }
    #pragma unroll
    for(int ct=0;ct<4;++ct){
      bf16x8 bfr = *(const bf16x8*)(kvw + (w*64 + ct*16 + li)*256 + ks*32 + g*8);
      #pragma unroll
      for(int rt=0;rt<4;++rt)
        acc[rt][ct] = __builtin_amdgcn_mfma_f32_16x16x32_bf16(a[rt], bfr, acc[rt][ct], 0,0,0);
    }
  }
  __syncthreads();   // x image dead

  // qf prefetch (global, B-frag for 32x32x16: col n = l31 (+nt*32), k = ks*16 + hi*8 + j)
  const int h = w;   // this wave's head
  bf16x8 qf[2][2];
  #pragma unroll
  for(int nt=0;nt<2;++nt)
    #pragma unroll
    for(int ks=0;ks<2;++ks)
      qf[nt][ks] = *(const bf16x8*)(q_s + (nt*32 + l31)*256 + h*32 + ks*16 + hi*8);

  // ---------- Phase 1b: waves 0..3 publish k (cols 0..255) ----------
  if(w < 4){
    #pragma unroll
    for(int ct=0;ct<4;++ct){
      int col = w*64 + ct*16 + li;
      #pragma unroll
      for(int rt=0;rt<4;++rt)
        #pragma unroll
        for(int r=0;r<4;++r){
          int row = rt*16 + 4*g + r;
          *(u16*)(R1 + ((row*512 + col*2) ^ ((row&7)<<4))) = f2bf(acc[rt][ct][r]);
        }
    }
  }
  __syncthreads();   // k visible

  // ---------- Phase 2: all waves preload kf (A-frag 32x32x16: row m = l31 (+mt*32), k = ks*16+hi*8+j) ----------
  bf16x8 kf[2][2];
  #pragma unroll
  for(int mt=0;mt<2;++mt)
    #pragma unroll
    for(int ks=0;ks<2;++ks){
      int row = mt*32 + l31;
      kf[mt][ks] = *(const bf16x8*)(R1 + ((row*512 + (h*32 + ks*16 + hi*8)*2) ^ ((row&7)<<4)));
    }
  __syncthreads();   // k dead

  // ---------- Phase 1c: waves 4..7 publish vT (from still-live acc) ----------
  if(w >= 4){
    #pragma unroll
    for(int ct=0;ct<4;++ct){
      int c2 = (w-4)*64 + ct*16 + li;     // 0..255
      int hv = c2>>5, e = c2&31;
      #pragma unroll
      for(int rt=0;rt<4;++rt){
        u32x2v d;
        d[0] = pack2(acc[rt][ct][0], acc[rt][ct][1]);
        d[1] = pack2(acc[rt][ct][2], acc[rt][ct][3]);
        int m0 = rt*16 + 4*g;
        *(u32x2v*)(R1 + (((hv*32 + e)*128 + m0*2) ^ ((e&7)<<4))) = d;
      }
    }
  }
  __syncthreads();   // vT visible

  // ---------- Phase 3: attention, wave w = head h ----------
  // S^T tiles: S[mt][nt], D-layout: col n = nt*32+l31, row m = mt*32 + (reg&3)+8*(reg>>2)+4*hi
  f32x16 S[2][2];
  #pragma unroll
  for(int mt=0;mt<2;++mt)
    #pragma unroll
    for(int nt=0;nt<2;++nt){
      int n = nt*32 + l31;
      const float* bp = bias + h*4096 + n*64 + mt*32 + 4*hi;
      #pragma unroll
      for(int q=0;q<4;++q){
        float4 bv = *(const float4*)(bp + q*8);
        S[mt][nt][4*q+0] = bv.x; S[mt][nt][4*q+1] = bv.y;
        S[mt][nt][4*q+2] = bv.z; S[mt][nt][4*q+3] = bv.w;
      }
    }
  #pragma unroll
  for(int ks=0;ks<2;++ks)
    #pragma unroll
    for(int mt=0;mt<2;++mt)
      #pragma unroll
      for(int nt=0;nt<2;++nt)
        S[mt][nt] = __builtin_amdgcn_mfma_f32_32x32x16_bf16(kf[mt][ks], qf[nt][ks], S[mt][nt], 0,0,0);

  // softmax over m (rows of S^T): 32 local values + partner lane (l^32)
  float rs[2];
  u32 cb0[2][8], cb1[2][8];
  #pragma unroll
  for(int nt=0;nt<2;++nt){
    float t[16];
    #pragma unroll
    for(int j=0;j<16;++j) t[j] = fmaxf(S[0][nt][j], S[1][nt][j]);
    #pragma unroll
    for(int s=8;s>0;s>>=1)
      #pragma unroll
      for(int j=0;j<8;++j) if(j<s) t[j] = fmaxf(t[j], t[j+s]);
    float mx = fmaxf(t[0], __shfl_xor(t[0], 32));
    float sm[16];
    #pragma unroll
    for(int j=0;j<16;++j){
      S[0][nt][j] = __expf(S[0][nt][j] - mx);
      S[1][nt][j] = __expf(S[1][nt][j] - mx);
      sm[j] = S[0][nt][j] + S[1][nt][j];
    }
    #pragma unroll
    for(int s=8;s>0;s>>=1)
      #pragma unroll
      for(int j=0;j<8;++j) if(j<s) sm[j] += sm[j+s];
    float total = sm[0] + __shfl_xor(sm[0], 32);
    rs[nt] = 1.0f/total;
    // pack P to bf16 pairs: block b = mt*4+q holds m = 32mt+8q+4hi + {0..3}
    #pragma unroll
    for(int mt=0;mt<2;++mt)
      #pragma unroll
      for(int q=0;q<4;++q){
        cb0[nt][mt*4+q] = pack2(S[mt][nt][4*q+0], S[mt][nt][4*q+1]);
        cb1[nt][mt*4+q] = pack2(S[mt][nt][4*q+2], S[mt][nt][4*q+3]);
      }
  }

  // O^T = V^T · P^T : A-frag vf (row e = l31, k m = ks2*16+hi*8+j), B-frag pf built in-register
  f32x16 O[2];
  O[0] = (f32x16)(0.f); O[1] = (f32x16)(0.f);
  #pragma unroll
  for(int ks2=0;ks2<4;++ks2){
    bf16x8 vf = *(const bf16x8*)(R1 + (((h*32 + l31)*128 + (ks2*16 + hi*8)*2) ^ ((l31&7)<<4)));
    #pragma unroll
    for(int nt=0;nt<2;++nt){
      // lane needs m-block b_t = 2*ks2 + hi: words0/1 from lane-lo's cb[b_t], words2/3 from lane-hi's cb[b_t]
      u32 A0 = cb0[nt][2*ks2], B0 = cb0[nt][2*ks2+1];
      u32 A1 = cb1[nt][2*ks2], B1 = cb1[nt][2*ks2+1];
      u32 r0 = (u32)__shfl_xor((int)(hi ? A0 : B0), 32);
      u32 r1 = (u32)__shfl_xor((int)(hi ? A1 : B1), 32);
      u32 w0 = hi ? r0 : A0;
      u32 w1 = hi ? r1 : A1;
      u32 w2 = hi ? B0 : r0;
      u32 w3 = hi ? B1 : r1;
      UV t; t.u = (u32x4v){w0,w1,w2,w3};
      O[nt] = __builtin_amdgcn_mfma_f32_32x32x16_bf16(vf, t.v, O[nt], 0,0,0);
    }
  }

  // epilogue: scale by 1/rowsum, pack, store ao chunk h (overwrites own vT chunk; e = (reg&3)+8q+4hi)
  #pragma unroll
  for(int nt=0;nt<2;++nt){
    int n = nt*32 + l31;
    #pragma unroll
    for(int q=0;q<4;++q){
      u32x2v d;
      d[0] = pack2(O[nt][4*q+0]*rs[nt], O[nt][4*q+1]*rs[nt]);
      d[1] = pack2(O[nt][4*q+2]*rs[nt], O[nt][4*q+3]*rs[nt]);
      *(u32x2v*)(R1 + h*4096 + ((n*64 + (8*q + 4*hi)*2) ^ ((n&7)<<4))) = d;
    }
  }
  __syncthreads();   // ao visible

  // ---------- Phase 4: proj GEMM. wave w -> out cols w*32..w*32+31 ----------
  {
    f32x4 pacc[4][2];
    #pragma unroll
    for(int ct=0;ct<2;++ct){
      float bv = proj_b[w*32 + ct*16 + li];
      #pragma unroll
      for(int rt=0;rt<4;++rt) pacc[rt][ct] = (f32x4){bv,bv,bv,bv};
    }
    for(int ks=0;ks<8;++ks){   // K-chunk ks = ao head-chunk ks (32 chans per head)
      bf16x8 a[4];
      #pragma unroll
      for(int rt=0;rt<4;++rt){
        int row = rt*16 + li;
        a[rt] = *(const bf16x8*)(R1 + ks*4096 + ((row*64 + g*16) ^ ((row&7)<<4)));
      }
      #pragma unroll
      for(int ct=0;ct<2;++ct){
        bf16x8 bfr = *(const bf16x8*)(pjw + (w*32 + ct*16 + li)*256 + ks*32 + g*8);
        #pragma unroll
        for(int rt=0;rt<4;++rt)
          pacc[rt][ct] = __builtin_amdgcn_mfma_f32_16x16x32_bf16(a[rt], bfr, pacc[rt][ct], 0,0,0);
      }
    }
    #pragma unroll
    for(int rt=0;rt<4;++rt)
      #pragma unroll
      for(int ct=0;ct<2;++ct)
        #pragma unroll
        for(int r=0;r<4;++r)
          out[(bw*64 + rt*16 + 4*g + r)*256 + w*32 + ct*16 + li] = pacc[rt][ct][r];
  }
}

extern "C" void kernel_launch(void* const* d_in, const int* in_sizes, int n_in,
                              void* d_out, int out_size, void* d_ws, size_t ws_size,
                              hipStream_t stream){
  (void)in_sizes; (void)n_in; (void)out_size;
  const float* x      = (const float*)d_in[0];
  const float* emb    = (const float*)d_in[1];
  const float* rpb    = (const float*)d_in[2];
  const float* q_w    = (const float*)d_in[3];
  const float* q_b    = (const float*)d_in[4];
  const float* kv_w   = (const float*)d_in[5];
  const float* kv_b   = (const float*)d_in[6];
  const float* proj_w = (const float*)d_in[7];
  const float* proj_b = (const float*)d_in[8];
  float* out = (float*)d_out;

  // ws layout (bytes): q_s 32K | bias 128K | kvw_bf 256K | pjw_bf 128K
  char* ws = (char*)d_ws;
  if(ws_size < (size_t)557056) return;   // diagnostic: out stays zero if ws too small
  u16* q_s   = (u16*)(ws);
  float* bias= (float*)(ws + 32768);
  u32* kvb   = (u32*)(ws + 163840);
  u32* pjb   = (u32*)(ws + 425984);

  k_qs   <<<  64, 256, 0, stream>>>(emb, q_w, q_b, q_s);
  k_bias <<< 128, 256, 0, stream>>>(rpb, bias);
  k_wcvt <<< 384, 256, 0, stream>>>(kv_w, proj_w, kvb, pjb);
  k_fused<<<2048, 512, 0, stream>>>(x, (const u16*)kvb, kv_b, q_s, bias,
                                    (const u16*)pjb, proj_b, out);
}

// Round 6
// 360.466 us; speedup vs baseline: 1.4451x; 1.0117x over previous
//
#include <hip/hip_runtime.h>

typedef short bf16x8 __attribute__((ext_vector_type(8)));
typedef float f32x4 __attribute__((ext_vector_type(4)));
typedef float f32x16 __attribute__((ext_vector_type(16)));
typedef unsigned u32;
typedef unsigned short u16;
typedef unsigned u32x4v __attribute__((ext_vector_type(4)));
typedef unsigned u32x2v __attribute__((ext_vector_type(2)));

union UV { u32x4v u; bf16x8 v; };

__device__ __forceinline__ u16 f2bf(float f){          // RNE fp32->bf16 (cold paths)
  u32 u = __float_as_uint(f);
  u += 0x7FFFu + ((u>>16)&1u);
  return (u16)(u>>16);
}
// hot-path pair conversion: single v_cvt_pk_bf16_f32 (no builtin on gfx950 -> inline asm, T12 recipe)
__device__ __forceinline__ u32 pack2(float lo, float hi){
  u32 r;
  asm("v_cvt_pk_bf16_f32 %0, %1, %2" : "=v"(r) : "v"(lo), "v"(hi));
  return r;
}

#define LOG2E 1.4426950408889634f

// ---------------- K0a: q_scaled[n][d] = SCALE*log2e*(emb[n,:]·q_w[d,:] + q_b[d]) -> bf16 ----------------
__global__ void k_qs(const float* __restrict__ emb, const float* __restrict__ q_w,
                     const float* __restrict__ q_b, u16* __restrict__ q_s){
  const int n = blockIdx.x;      // 64
  const int d = threadIdx.x;     // 256
  const float4* er = (const float4*)(emb + n*256);
  const float4* wr = (const float4*)(q_w + d*256);
  float acc = 0.f;
  for(int c=0;c<64;++c){
    float4 e = er[c], w = wr[c];
    acc += e.x*w.x + e.y*w.y + e.z*w.z + e.w*w.w;
  }
  acc += q_b[d];
  q_s[n*256 + d] = f2bf(acc * (0.17677669529663687f * LOG2E));   // 32^-0.5 * log2e
}

// ---------------- K0b: bias[h][n][m] = rpb[rel_idx(n,m)][h] * log2e (fp32) ----------------
__global__ void k_bias(const float* __restrict__ rpb, float* __restrict__ bias){
  const int o = blockIdx.x*256 + threadIdx.x;          // 128 blocks -> 32768
  const int h = o>>12, n = (o>>6)&63, m = o&63;
  const int idx = ((n>>3)-(m>>3)+7)*15 + ((n&7)-(m&7)+7);
  bias[o] = rpb[idx*8 + h] * LOG2E;
}

// ---------------- K0c: convert kv_w (131072 f32) and proj_w (65536 f32) to bf16 ----------------
__global__ void k_wcvt(const float* __restrict__ kv_w, const float* __restrict__ proj_w,
                       u32* __restrict__ kvb, u32* __restrict__ pjb){
  const int i = blockIdx.x*256 + threadIdx.x;          // 384 blocks -> 98304
  if(i < 65536) kvb[i] = pack2(kv_w[2*i], kv_w[2*i+1]);
  else { int j = i - 65536; pjb[j] = pack2(proj_w[2*j], proj_w[2*j+1]); }
}

// ---------------- Fused per-window kernel, 8 waves, one head per wave ----------------
// Single 32KB LDS region, reused in sequence:
//   x_bf16[64 tok][256 ch] swz  ->  k[64 tok][256 ch] swz  ->  vT[8 h][32 e][64 m] swz
//   -> ao[8 h][64 n][32 e] swz (per-head chunk overwrites own vT chunk)
// swizzles: row-major tiles use byte ^= ((row&7)<<4)
__global__ __launch_bounds__(512,4) void k_fused(const float* __restrict__ x, const u16* __restrict__ kvw,
                                                 const float* __restrict__ kv_b, const u16* __restrict__ q_s,
                                                 const float* __restrict__ bias, const u16* __restrict__ pjw,
                                                 const float* __restrict__ proj_b, float* __restrict__ out){
  __shared__ char R1[32768];

  const int bw = blockIdx.x;
  const int b = bw>>8, h1 = (bw>>4)&15, w1 = bw&15;
  const int base = b*4194304 + h1*262144 + w1*2048;
  const int tid = threadIdx.x;
  const int w = tid>>6, l = tid&63, g = l>>4, li = l&15;
  const int l31 = l&31, hi = l>>5;

  // ---------- Phase 0: cooperative stage x window -> R1 as bf16 (swizzled) ----------
  #pragma unroll
  for(int i=0;i<4;++i){
    int p = i*512 + tid;                 // 16B-pair index 0..2047
    int n = p>>5;                        // token row 0..63
    int c4 = (2*p)&63;                   // f4 index within row (even)
    const float4* gp = (const float4*)(x + base + (n>>3)*32768 + (n&7)*256 + c4*4);
    float4 lo = gp[0], hh = gp[1];
    u32x4v d = { pack2(lo.x,lo.y), pack2(lo.z,lo.w), pack2(hh.x,hh.y), pack2(hh.z,hh.w) };
    *(u32x4v*)(R1 + ((p*16) ^ ((n&7)<<4))) = d;
  }
  __syncthreads();

  // ---------- Phase 1: KV GEMM. wave w computes output cols w*64..w*64+63 ----------
  f32x4 acc[4][4];
  #pragma unroll
  for(int ct=0;ct<4;++ct){
    float bv = kv_b[w*64 + ct*16 + li];
    #pragma unroll
    for(int rt=0;rt<4;++rt) acc[rt][ct] = (f32x4){bv,bv,bv,bv};
  }
  {
    const u16* wbase = kvw + (w*64 + li)*256 + g*8;   // + ct*4096 + ks*32
    bf16x8 bcur[4];
    #pragma unroll
    for(int ct=0;ct<4;++ct) bcur[ct] = *(const bf16x8*)(wbase + ct*4096);
    #pragma unroll
    for(int ks=0;ks<8;++ks){
      bf16x8 a[4];
      #pragma unroll
      for(int rt=0;rt<4;++rt){
        int n = rt*16 + li;
        a[rt] = *(const bf16x8*)(R1 + ((n*512 + ks*64 + g*16) ^ ((n&7)<<4)));
      }
      #pragma unroll
      for(int ct=0;ct<4;++ct){
        #pragma unroll
        for(int rt=0;rt<4;++rt)
          acc[rt][ct] = __builtin_amdgcn_mfma_f32_16x16x32_bf16(a[rt], bcur[ct], acc[rt][ct], 0,0,0);
        if(ks<7) bcur[ct] = *(const bf16x8*)(wbase + ct*4096 + (ks+1)*32);  // load-after-use prefetch
      }
    }
  }
  __syncthreads();   // x image dead

  // qf prefetch (global, B-frag for 32x32x16: col n = l31 (+nt*32), k = ks*16 + hi*8 + j)
  const int h = w;   // this wave's head
  bf16x8 qf[2][2];
  #pragma unroll
  for(int nt=0;nt<2;++nt)
    #pragma unroll
    for(int ks=0;ks<2;++ks)
      qf[nt][ks] = *(const bf16x8*)(q_s + (nt*32 + l31)*256 + h*32 + ks*16 + hi*8);

  // ---------- Phase 1b: waves 0..3 publish k (cols 0..255), lane-paired u32 writes ----------
  const int oddl = li & 1;
  if(w < 4){
    #pragma unroll
    for(int ct=0;ct<4;++ct){
      int colp = w*64 + ct*16 + (li & ~1);   // even col of the pair
      #pragma unroll
      for(int rt=0;rt<4;++rt){
        float v0=acc[rt][ct][0], v1=acc[rt][ct][1], v2=acc[rt][ct][2], v3=acc[rt][ct][3];
        float o0=__shfl_xor(v0,1), o1=__shfl_xor(v1,1), o2=__shfl_xor(v2,1), o3=__shfl_xor(v3,1);
        u32 d0 = oddl ? pack2(o2,v2) : pack2(v0,o0);
        u32 d1 = oddl ? pack2(o3,v3) : pack2(v1,o1);
        int row0 = rt*16 + 4*g + (oddl ? 2 : 0);
        *(u32*)(R1 + ((row0*512     + colp*2) ^ ((row0&7)<<4)))     = d0;
        *(u32*)(R1 + (((row0+1)*512 + colp*2) ^ (((row0+1)&7)<<4))) = d1;
      }
    }
  }
  __syncthreads();   // k visible

  // ---------- Phase 2: all waves preload kf (A-frag 32x32x16: row m = l31 (+mt*32), k = ks*16+hi*8+j) ----------
  bf16x8 kf[2][2];
  #pragma unroll
  for(int mt=0;mt<2;++mt)
    #pragma unroll
    for(int ks=0;ks<2;++ks){
      int row = mt*32 + l31;
      kf[mt][ks] = *(const bf16x8*)(R1 + ((row*512 + (h*32 + ks*16 + hi*8)*2) ^ ((row&7)<<4)));
    }
  __syncthreads();   // k dead

  // ---------- Phase 1c: waves 4..7 publish vT (from still-live acc) ----------
  if(w >= 4){
    #pragma unroll
    for(int ct=0;ct<4;++ct){
      int c2 = (w-4)*64 + ct*16 + li;     // 0..255
      int hv = c2>>5, e = c2&31;
      #pragma unroll
      for(int rt=0;rt<4;++rt){
        u32x2v d;
        d[0] = pack2(acc[rt][ct][0], acc[rt][ct][1]);
        d[1] = pack2(acc[rt][ct][2], acc[rt][ct][3]);
        int m0 = rt*16 + 4*g;
        *(u32x2v*)(R1 + (((hv*32 + e)*128 + m0*2) ^ ((e&7)<<4))) = d;
      }
    }
  }
  __syncthreads();   // vT visible

  // ---------- Phase 3: attention, wave w = head h ----------
  // S^T tiles: S[mt][nt], D-layout: col n = nt*32+l31, row m = mt*32 + (reg&3)+8*(reg>>2)+4*hi
  f32x16 S[2][2];
  #pragma unroll
  for(int mt=0;mt<2;++mt)
    #pragma unroll
    for(int nt=0;nt<2;++nt){
      int n = nt*32 + l31;
      const float* bp = bias + h*4096 + n*64 + mt*32 + 4*hi;
      #pragma unroll
      for(int q=0;q<4;++q){
        float4 bv = *(const float4*)(bp + q*8);
        S[mt][nt][4*q+0] = bv.x; S[mt][nt][4*q+1] = bv.y;
        S[mt][nt][4*q+2] = bv.z; S[mt][nt][4*q+3] = bv.w;
      }
    }
  #pragma unroll
  for(int ks=0;ks<2;++ks)
    #pragma unroll
    for(int mt=0;mt<2;++mt)
      #pragma unroll
      for(int nt=0;nt<2;++nt)
        S[mt][nt] = __builtin_amdgcn_mfma_f32_32x32x16_bf16(kf[mt][ks], qf[nt][ks], S[mt][nt], 0,0,0);

  // softmax over m (rows of S^T): 32 local values + partner lane (l^32); S is in log2-units
  float rs[2];
  u32 cb0[2][8], cb1[2][8];
  #pragma unroll
  for(int nt=0;nt<2;++nt){
    float t[16];
    #pragma unroll
    for(int j=0;j<16;++j) t[j] = fmaxf(S[0][nt][j], S[1][nt][j]);
    #pragma unroll
    for(int s=8;s>0;s>>=1)
      #pragma unroll
      for(int j=0;j<8;++j) if(j<s) t[j] = fmaxf(t[j], t[j+s]);
    float mx = fmaxf(t[0], __shfl_xor(t[0], 32));
    float sm[16];
    #pragma unroll
    for(int j=0;j<16;++j){
      S[0][nt][j] = __builtin_amdgcn_exp2f(S[0][nt][j] - mx);
      S[1][nt][j] = __builtin_amdgcn_exp2f(S[1][nt][j] - mx);
      sm[j] = S[0][nt][j] + S[1][nt][j];
    }
    #pragma unroll
    for(int s=8;s>0;s>>=1)
      #pragma unroll
      for(int j=0;j<8;++j) if(j<s) sm[j] += sm[j+s];
    float total = sm[0] + __shfl_xor(sm[0], 32);
    rs[nt] = 1.0f/total;
    // pack P to bf16 pairs: block b = mt*4+q holds m = 32mt+8q+4hi + {0..3}
    #pragma unroll
    for(int mt=0;mt<2;++mt)
      #pragma unroll
      for(int q=0;q<4;++q){
        cb0[nt][mt*4+q] = pack2(S[mt][nt][4*q+0], S[mt][nt][4*q+1]);
        cb1[nt][mt*4+q] = pack2(S[mt][nt][4*q+2], S[mt][nt][4*q+3]);
      }
  }

  // O^T = V^T · P^T : A-frag vf (row e = l31, k m = ks2*16+hi*8+j), B-frag pf built in-register
  f32x16 O[2];
  O[0] = (f32x16)(0.f); O[1] = (f32x16)(0.f);
  #pragma unroll
  for(int ks2=0;ks2<4;++ks2){
    bf16x8 vf = *(const bf16x8*)(R1 + (((h*32 + l31)*128 + (ks2*16 + hi*8)*2) ^ ((l31&7)<<4)));
    #pragma unroll
    for(int nt=0;nt<2;++nt){
      // lane needs m-block b_t = 2*ks2 + hi: words0/1 from lane-lo's cb[b_t], words2/3 from lane-hi's cb[b_t]
      u32 A0 = cb0[nt][2*ks2], B0 = cb0[nt][2*ks2+1];
      u32 A1 = cb1[nt][2*ks2], B1 = cb1[nt][2*ks2+1];
      u32 r0 = (u32)__shfl_xor((int)(hi ? A0 : B0), 32);
      u32 r1 = (u32)__shfl_xor((int)(hi ? A1 : B1), 32);
      u32 w0 = hi ? r0 : A0;
      u32 w1 = hi ? r1 : A1;
      u32 w2 = hi ? B0 : r0;
      u32 w3 = hi ? B1 : r1;
      UV t; t.u = (u32x4v){w0,w1,w2,w3};
      O[nt] = __builtin_amdgcn_mfma_f32_32x32x16_bf16(vf, t.v, O[nt], 0,0,0);
    }
  }

  // epilogue: scale by 1/rowsum, pack, store ao chunk h (overwrites own vT chunk; e = (reg&3)+8q+4hi)
  #pragma unroll
  for(int nt=0;nt<2;++nt){
    int n = nt*32 + l31;
    #pragma unroll
    for(int q=0;q<4;++q){
      u32x2v d;
      d[0] = pack2(O[nt][4*q+0]*rs[nt], O[nt][4*q+1]*rs[nt]);
      d[1] = pack2(O[nt][4*q+2]*rs[nt], O[nt][4*q+3]*rs[nt]);
      *(u32x2v*)(R1 + h*4096 + ((n*64 + (8*q + 4*hi)*2) ^ ((n&7)<<4))) = d;
    }
  }
  __syncthreads();   // ao visible

  // ---------- Phase 4: proj GEMM. wave w -> out cols w*32..w*32+31 ----------
  {
    f32x4 pacc[4][2];
    #pragma unroll
    for(int ct=0;ct<2;++ct){
      float bv = proj_b[w*32 + ct*16 + li];
      #pragma unroll
      for(int rt=0;rt<4;++rt) pacc[rt][ct] = (f32x4){bv,bv,bv,bv};
    }
    const u16* pbase = pjw + (w*32 + li)*256 + g*8;    // + ct*4096 + ks*32
    bf16x8 bc[2];
    #pragma unroll
    for(int ct=0;ct<2;++ct) bc[ct] = *(const bf16x8*)(pbase + ct*4096);
    #pragma unroll
    for(int ks=0;ks<8;++ks){   // K-chunk ks = ao head-chunk ks (32 chans per head)
      bf16x8 a[4];
      #pragma unroll
      for(int rt=0;rt<4;++rt){
        int row = rt*16 + li;
        a[rt] = *(const bf16x8*)(R1 + ks*4096 + ((row*64 + g*16) ^ ((row&7)<<4)));
      }
      #pragma unroll
      for(int ct=0;ct<2;++ct){
        #pragma unroll
        for(int rt=0;rt<4;++rt)
          pacc[rt][ct] = __builtin_amdgcn_mfma_f32_16x16x32_bf16(a[rt], bc[ct], pacc[rt][ct], 0,0,0);
        if(ks<7) bc[ct] = *(const bf16x8*)(pbase + ct*4096 + (ks+1)*32);   // load-after-use prefetch
      }
    }
    #pragma unroll
    for(int rt=0;rt<4;++rt)
      #pragma unroll
      for(int ct=0;ct<2;++ct)
        #pragma unroll
        for(int r=0;r<4;++r)
          out[(bw*64 + rt*16 + 4*g + r)*256 + w*32 + ct*16 + li] = pacc[rt][ct][r];
  }
}

extern "C" void kernel_launch(void* const* d_in, const int* in_sizes, int n_in,
                              void* d_out, int out_size, void* d_ws, size_t ws_size,
                              hipStream_t stream){
  (void)in_sizes; (void)n_in; (void)out_size;
  const float* x      = (const float*)d_in[0];
  const float* emb    = (const float*)d_in[1];
  const float* rpb    = (const float*)d_in[2];
  const float* q_w    = (const float*)d_in[3];
  const float* q_b    = (const float*)d_in[4];
  const float* kv_w   = (const float*)d_in[5];
  const float* kv_b   = (const float*)d_in[6];
  const float* proj_w = (const float*)d_in[7];
  const float* proj_b = (const float*)d_in[8];
  float* out = (float*)d_out;

  // ws layout (bytes): q_s 32K | bias 128K | kvw_bf 256K | pjw_bf 128K
  char* ws = (char*)d_ws;
  if(ws_size < (size_t)557056) return;   // diagnostic: out stays zero if ws too small
  u16* q_s   = (u16*)(ws);
  float* bias= (float*)(ws + 32768);
  u32* kvb   = (u32*)(ws + 163840);
  u32* pjb   = (u32*)(ws + 425984);

  k_qs   <<<  64, 256, 0, stream>>>(emb, q_w, q_b, q_s);
  k_bias <<< 128, 256, 0, stream>>>(rpb, bias);
  k_wcvt <<< 384, 256, 0, stream>>>(kv_w, proj_w, kvb, pjb);
  k_fused<<<2048, 512, 0, stream>>>(x, (const u16*)kvb, kv_b, q_s, bias,
                                    (const u16*)pjb, proj_b, out);
}